// Round 2
// baseline (544.942 us; speedup 1.0000x reference)
//
#include <hip/hip_runtime.h>

#define NDIN 128
#define NDOUT 64

// ---------------------------------------------------------------------------
// Kernel 1: xw = x @ W   (f32 vector GEMM; K=128, N=64)
// block = 256 threads = 4 waves; wave r handles rows [blk*16 + r*4, +4)
// lane = output column (0..63). W staged in LDS [128][64] (32 KB).
// ---------------------------------------------------------------------------
__global__ __launch_bounds__(256) void gemm_xw_kernel(
    const float* __restrict__ x, const float* __restrict__ w,
    float* __restrict__ xw, int n_nodes) {
  __shared__ float wlds[NDIN][NDOUT];
  const int t = threadIdx.x;
  // cooperative load of W (8192 floats = 2048 float4, 256 threads -> 8 each)
  const float4* w4 = (const float4*)w;
  float4* wl4 = (float4*)(&wlds[0][0]);
#pragma unroll
  for (int i = 0; i < (NDIN * NDOUT / 4) / 256; ++i)
    wl4[t + i * 256] = w4[t + i * 256];
  __syncthreads();

  const int col = t & 63;
  const int r = t >> 6;  // wave id within block
  const int row0 = blockIdx.x * 16 + r * 4;
  if (row0 >= n_nodes) return;

  if (row0 + 3 < n_nodes) {
    const float* x0 = x + (size_t)row0 * NDIN;
    float acc0 = 0.f, acc1 = 0.f, acc2 = 0.f, acc3 = 0.f;
#pragma unroll
    for (int k = 0; k < NDIN; k += 4) {
      float4 a = *(const float4*)(x0 + k);
      float4 b = *(const float4*)(x0 + NDIN + k);
      float4 c = *(const float4*)(x0 + 2 * NDIN + k);
      float4 d = *(const float4*)(x0 + 3 * NDIN + k);
      float w0 = wlds[k][col], w1 = wlds[k + 1][col];
      float w2 = wlds[k + 2][col], w3 = wlds[k + 3][col];
      acc0 += a.x * w0 + a.y * w1 + a.z * w2 + a.w * w3;
      acc1 += b.x * w0 + b.y * w1 + b.z * w2 + b.w * w3;
      acc2 += c.x * w0 + c.y * w1 + c.z * w2 + c.w * w3;
      acc3 += d.x * w0 + d.y * w1 + d.z * w2 + d.w * w3;
    }
    xw[(size_t)row0 * NDOUT + col] = acc0;
    xw[(size_t)(row0 + 1) * NDOUT + col] = acc1;
    xw[(size_t)(row0 + 2) * NDOUT + col] = acc2;
    xw[(size_t)(row0 + 3) * NDOUT + col] = acc3;
  } else {
    for (int j = 0; j < 4; ++j) {
      int row = row0 + j;
      if (row >= n_nodes) break;
      const float* xr = x + (size_t)row * NDIN;
      float acc = 0.f;
      for (int k = 0; k < NDIN; k += 4) {
        float4 a = *(const float4*)(xr + k);
        acc += a.x * wlds[k][col] + a.y * wlds[k + 1][col] +
               a.z * wlds[k + 2][col] + a.w * wlds[k + 3][col];
      }
      xw[(size_t)row * NDOUT + col] = acc;
    }
  }
}

// ---------------------------------------------------------------------------
// Kernel 2: per edge e: out[src[e], :] += edge_weight[e] * xw[dst[e], :]
// one wave handles one edge per iteration; lane = column.
// ---------------------------------------------------------------------------
__global__ __launch_bounds__(256) void edge_scatter_kernel(
    const float* __restrict__ xw, const float* __restrict__ ew,
    const int* __restrict__ src, const int* __restrict__ dst,
    float* __restrict__ out, int n_edges) {
  const int lane = threadIdx.x & 63;
  const int wid = (blockIdx.x * 256 + threadIdx.x) >> 6;
  const int nw = (gridDim.x * 256) >> 6;
  for (int e = wid; e < n_edges; e += nw) {
    const int s = src[e];
    const int d = dst[e];
    const float w = ew[e];
    const float v = xw[(size_t)d * NDOUT + lane] * w;
    atomicAdd(out + (size_t)s * NDOUT + lane, v);
  }
}

// ---------------------------------------------------------------------------
// Kernel 3: in-place ReLU on out (float4-vectorized)
// ---------------------------------------------------------------------------
__global__ __launch_bounds__(256) void relu_kernel(float* __restrict__ out,
                                                   int n4) {
  float4* o4 = (float4*)out;
  int i = blockIdx.x * 256 + threadIdx.x;
  const int stride = gridDim.x * 256;
  for (; i < n4; i += stride) {
    float4 v = o4[i];
    v.x = fmaxf(v.x, 0.f);
    v.y = fmaxf(v.y, 0.f);
    v.z = fmaxf(v.z, 0.f);
    v.w = fmaxf(v.w, 0.f);
    o4[i] = v;
  }
}

extern "C" void kernel_launch(void* const* d_in, const int* in_sizes, int n_in,
                              void* d_out, int out_size, void* d_ws,
                              size_t ws_size, hipStream_t stream) {
  const float* x = (const float*)d_in[0];     // [N, 128]
  const float* ew = (const float*)d_in[1];    // [E]
  const float* w = (const float*)d_in[2];     // [128, 64]
  const int* esrc = (const int*)d_in[3];      // [E]
  const int* edst = (const int*)d_in[4];      // [E]
  float* out = (float*)d_out;                 // [N, 64]
  float* xw = (float*)d_ws;                   // [N, 64] scratch

  const int n_nodes = in_sizes[0] / NDIN;
  const int n_edges = in_sizes[1];

  // 1) xw = x @ W
  const int gblocks = (n_nodes + 15) / 16;
  gemm_xw_kernel<<<gblocks, 256, 0, stream>>>(x, w, xw, n_nodes);

  // 2) zero the output accumulator (harness poisons d_out with 0xAA)
  hipMemsetAsync(d_out, 0, (size_t)out_size * sizeof(float), stream);

  // 3) scatter-add messages
  edge_scatter_kernel<<<2048, 256, 0, stream>>>(xw, ew, esrc, edst, out,
                                                n_edges);

  // 4) ReLU
  relu_kernel<<<1024, 256, 0, stream>>>(out, out_size / 4);
}